// Round 1
// baseline (384.635 us; speedup 1.0000x reference)
//
#include <hip/hip_runtime.h>

typedef __attribute__((ext_vector_type(8))) short s16x8;
typedef __attribute__((ext_vector_type(4))) float f32x4;

#define F 128

__device__ __forceinline__ unsigned short f2bf(float f) {
    unsigned int u = __float_as_uint(f);
    u = (u + 0x7fffu + ((u >> 16) & 1u)) >> 16;
    return (unsigned short)u;
}
__device__ __forceinline__ float bflo(unsigned int u) { return __uint_as_float(u << 16); }
__device__ __forceinline__ float bfhi(unsigned int u) { return __uint_as_float(u & 0xffff0000u); }
__device__ __forceinline__ float leaky(float x) { return x >= 0.f ? x : 0.2f * x; }
__device__ __forceinline__ float sigmoidf(float x) { return 1.f / (1.f + __expf(-x)); }

// ---------------- kernel 0: transpose + bf16-convert both W ----------------
// wT[m][c][k] = bf16(W_m[k][c]),  m=0 ref, m=1 dir. 2*128*128 elements.
__global__ __launch_bounds__(256) void prep_w(const float* __restrict__ wRef,
                                              const float* __restrict__ wDir,
                                              unsigned short* __restrict__ wT) {
    int i = blockIdx.x * 256 + threadIdx.x;      // 0..32767
    int m = i >> 14;
    int r = i & 16383;
    int k = r >> 7;
    int c = r & 127;
    const float* W = m ? wDir : wRef;
    wT[m * 16384 + c * 128 + k] = f2bf(W[k * 128 + c]);
}

// ---------------- kernel 1: Wh = h @ W for both W, bf16 out ----------------
// block = 256 (4 waves); each wave does 16 rows x 128 cols, K=128.
// mfma_f32_16x16x32_bf16: A row = lane&15, k = 8*(lane>>4)+j ; B col = lane&15, same k.
// C/D: col = lane&15, row = (lane>>4)*4 + reg  [verified layout].
__global__ __launch_bounds__(256) void gemm_wh(const float* __restrict__ h,
                                               const unsigned short* __restrict__ wT,
                                               unsigned short* __restrict__ whRef,
                                               unsigned short* __restrict__ whDir,
                                               int N) {
    const int lane = threadIdx.x & 63;
    const int wid = threadIdx.x >> 6;
    const int r = lane & 15, g = lane >> 4;
    const int rowBase = blockIdx.x * 64 + wid * 16;
    const int arow = rowBase + r;

    // A fragments for all 4 k-steps (k = kt*32 + g*8 + j)
    s16x8 afr[4];
#pragma unroll
    for (int kt = 0; kt < 4; ++kt) {
        float x[8];
        if (arow < N) {
            const float* p = h + (size_t)arow * F + kt * 32 + g * 8;
            float4 v0 = *(const float4*)(p);
            float4 v1 = *(const float4*)(p + 4);
            x[0] = v0.x; x[1] = v0.y; x[2] = v0.z; x[3] = v0.w;
            x[4] = v1.x; x[5] = v1.y; x[6] = v1.z; x[7] = v1.w;
        } else {
#pragma unroll
            for (int j = 0; j < 8; ++j) x[j] = 0.f;
        }
        s16x8 a;
#pragma unroll
        for (int j = 0; j < 8; ++j) a[j] = (short)f2bf(x[j]);
        afr[kt] = a;
    }

#pragma unroll
    for (int m = 0; m < 2; ++m) {
        const unsigned short* wp = wT + m * 16384;
        unsigned short* dst = m ? whDir : whRef;
        f32x4 acc[8];
#pragma unroll
        for (int ct = 0; ct < 8; ++ct) acc[ct] = (f32x4){0.f, 0.f, 0.f, 0.f};
#pragma unroll
        for (int kt = 0; kt < 4; ++kt) {
#pragma unroll
            for (int ct = 0; ct < 8; ++ct) {
                s16x8 b = *(const s16x8*)(wp + (ct * 16 + r) * 128 + kt * 32 + g * 8);
                acc[ct] = __builtin_amdgcn_mfma_f32_16x16x32_bf16(afr[kt], b, acc[ct], 0, 0, 0);
            }
        }
#pragma unroll
        for (int ct = 0; ct < 8; ++ct) {
#pragma unroll
            for (int q = 0; q < 4; ++q) {
                int orow = rowBase + g * 4 + q;
                if (orow < N) dst[(size_t)orow * F + ct * 16 + r] = f2bf(acc[ct][q]);
            }
        }
    }
}

// ---------------- kernel 2: per-node scalars s,t for both branches ----------------
__global__ __launch_bounds__(256) void scalars_k(const unsigned short* __restrict__ whRef,
                                                 const unsigned short* __restrict__ whDir,
                                                 const float* __restrict__ aRef,
                                                 const float* __restrict__ aDir,
                                                 float* __restrict__ sRef, float* __restrict__ tRef,
                                                 float* __restrict__ sDir, float* __restrict__ tDir,
                                                 int N) {
    int gw = (int)((blockIdx.x * 256 + threadIdx.x) >> 6);
    int lane = threadIdx.x & 63;
    if (gw >= N) return;
    unsigned int ur = *(const unsigned int*)(whRef + (size_t)gw * F + lane * 2);
    unsigned int ud = *(const unsigned int*)(whDir + (size_t)gw * F + lane * 2);
    float r0 = bflo(ur), r1 = bfhi(ur), d0 = bflo(ud), d1 = bfhi(ud);
    float vsr = r0 * aRef[2 * lane] + r1 * aRef[2 * lane + 1];
    float vtr = r0 * aRef[128 + 2 * lane] + r1 * aRef[128 + 2 * lane + 1];
    float vsd = d0 * aDir[2 * lane] + d1 * aDir[2 * lane + 1];
    float vtd = d0 * aDir[128 + 2 * lane] + d1 * aDir[128 + 2 * lane + 1];
#pragma unroll
    for (int off = 32; off; off >>= 1) {
        vsr += __shfl_xor(vsr, off);
        vtr += __shfl_xor(vtr, off);
        vsd += __shfl_xor(vsd, off);
        vtd += __shfl_xor(vtd, off);
    }
    if (lane == 0) {
        sRef[gw] = vsr; tRef[gw] = vtr; sDir[gw] = vsd; tDir[gw] = vtd;
    }
}

// ---------------- kernel 3: gather + attention + output ----------------
// one wave per node; 4 waves (nodes) per block.
__global__ __launch_bounds__(256) void gather_attn(
    const unsigned short* __restrict__ whRef, const unsigned short* __restrict__ whDir,
    const float* __restrict__ sRef, const float* __restrict__ tRef,
    const float* __restrict__ sDir, const float* __restrict__ tDir,
    const int* __restrict__ refNbr, const int* __restrict__ refCnt,
    const int* __restrict__ dirNbr, const int* __restrict__ dirCnt,
    float* __restrict__ out, int N) {
    __shared__ int s_ridx[4][40];
    __shared__ float s_rt[4][40];
    __shared__ int s_didx[4][32];
    __shared__ float s_dcoef[4][32];
    __shared__ int s_rcnt[4][4];
    __shared__ float s_rcoef[4][4];

    const int wid = threadIdx.x >> 6;
    const int lane = threadIdx.x & 63;
    const int n_raw = blockIdx.x * 4 + wid;
    const int n = n_raw < N ? n_raw : N - 1;

    // ---- phase A: load indices / scalar gathers into LDS ----
    if (lane < 40) {
        int idx = refNbr[(size_t)n * 40 + lane];
        s_ridx[wid][lane] = idx;
        s_rt[wid][lane] = tRef[idx];
    }
    if (lane < 4) s_rcnt[wid][lane] = refCnt[n * 4 + lane];
    float dt = 0.f;
    if (lane < 32) {
        int idx = dirNbr[(size_t)n * 32 + lane];
        s_didx[wid][lane] = idx;
        dt = tDir[idx];
    }
    const int dcnt = dirCnt[n];
    const float sR = sRef[n], sD = sDir[n];
    __syncthreads();

    // ---- phase B1: ref logits (all lanes redundantly; LDS broadcasts) ----
    float e[4];
#pragma unroll
    for (int d = 0; d < 4; ++d) {
        int c = s_rcnt[wid][d];
        float sum = 0.f;
#pragma unroll
        for (int k = 0; k < 10; ++k) sum += (k < c) ? s_rt[wid][d * 10 + k] : 0.f;
        float cc = (float)(c > 0 ? c : 1);
        e[d] = leaky(sR + sum / cc);
    }
    float mr = fmaxf(fmaxf(e[0], e[1]), fmaxf(e[2], e[3]));
    float w0 = __expf(e[0] - mr), w1 = __expf(e[1] - mr), w2 = __expf(e[2] - mr), w3 = __expf(e[3] - mr);
    float den = w0 + w1 + w2 + w3;
    if (lane < 4) {
        float w = lane == 0 ? w0 : (lane == 1 ? w1 : (lane == 2 ? w2 : w3));
        int c = s_rcnt[wid][lane];
        s_rcoef[wid][lane] = w / den / (float)(c > 0 ? c : 1);
    }

    // ---- phase B2: dir logits + 32-lane softmax ----
    float ed = -1e30f;
    if (lane < 32) ed = (lane < dcnt) ? leaky(sD + dt) : -1e30f;
    float md = ed;
#pragma unroll
    for (int off = 16; off; off >>= 1) md = fmaxf(md, __shfl_xor(md, off, 32));
    float wd = __expf(ed - md);
    float dd = wd;
#pragma unroll
    for (int off = 16; off; off >>= 1) dd += __shfl_xor(dd, off, 32);
    if (lane < 32) s_dcoef[wid][lane] = wd / dd;
    __syncthreads();

    // ---- phase C: weighted row gathers (features 2*lane, 2*lane+1) ----
    float a0 = 0.f, a1 = 0.f;
#pragma unroll
    for (int d = 0; d < 4; ++d) {
        int c = s_rcnt[wid][d];
        float coef = s_rcoef[wid][d];
        for (int k = 0; k < c; ++k) {   // wave-uniform trip count
            int idx = s_ridx[wid][d * 10 + k];
            unsigned int u = *(const unsigned int*)(whRef + (size_t)idx * F + 2 * lane);
            a0 += coef * bflo(u);
            a1 += coef * bfhi(u);
        }
    }
    float b0 = 0.f, b1 = 0.f;
    for (int k = 0; k < dcnt; ++k) {    // wave-uniform trip count
        float coef = s_dcoef[wid][k];
        int idx = s_didx[wid][k];
        unsigned int u = *(const unsigned int*)(whDir + (size_t)idx * F + 2 * lane);
        b0 += coef * bflo(u);
        b1 += coef * bfhi(u);
    }

    if (n_raw < N) {
        float o0 = 0.5f * (sigmoidf(a0) + sigmoidf(b0));
        float o1 = 0.5f * (sigmoidf(a1) + sigmoidf(b1));
        *(float2*)(out + (size_t)n * F + 2 * lane) = make_float2(o0, o1);
    }
}

extern "C" void kernel_launch(void* const* d_in, const int* in_sizes, int n_in,
                              void* d_out, int out_size, void* d_ws, size_t ws_size,
                              hipStream_t stream) {
    const float* h    = (const float*)d_in[0];
    const float* Wref = (const float*)d_in[1];
    const float* aRef = (const float*)d_in[2];
    const float* Wdir = (const float*)d_in[3];
    const float* aDir = (const float*)d_in[4];
    const int* refNbr = (const int*)d_in[5];
    const int* refCnt = (const int*)d_in[6];
    const int* dirNbr = (const int*)d_in[7];
    const int* dirCnt = (const int*)d_in[8];
    float* out = (float*)d_out;
    const int N = in_sizes[0] / F;

    const size_t NF = (size_t)N * F;
    unsigned short* whRef = (unsigned short*)d_ws;          // NF bf16
    unsigned short* whDir = whRef + NF;                     // NF bf16
    float* sRef = (float*)(whDir + NF);
    float* tRef = sRef + N;
    float* sDir = tRef + N;
    float* tDir = sDir + N;
    unsigned short* wT = (unsigned short*)(tDir + N);       // 2*128*128 bf16

    prep_w<<<128, 256, 0, stream>>>(Wref, Wdir, wT);
    gemm_wh<<<(N + 63) / 64, 256, 0, stream>>>(h, wT, whRef, whDir, N);
    scalars_k<<<(N + 3) / 4, 256, 0, stream>>>(whRef, whDir, aRef, aDir, sRef, tRef, sDir, tDir, N);
    gather_attn<<<(N + 3) / 4, 256, 0, stream>>>(whRef, whDir, sRef, tRef, sDir, tDir,
                                                 refNbr, refCnt, dirNbr, dirCnt, out, N);
}

// Round 3
// 308.257 us; speedup vs baseline: 1.2478x; 1.2478x over previous
//
#include <hip/hip_runtime.h>

typedef __attribute__((ext_vector_type(8))) short s16x8;
typedef __attribute__((ext_vector_type(4))) float f32x4;

#define F 128

__device__ __forceinline__ unsigned short f2bf(float f) {
    unsigned int u = __float_as_uint(f);
    u = (u + 0x7fffu + ((u >> 16) & 1u)) >> 16;
    return (unsigned short)u;
}
__device__ __forceinline__ float bflo(unsigned int u) { return __uint_as_float(u << 16); }
__device__ __forceinline__ float bfhi(unsigned int u) { return __uint_as_float(u & 0xffff0000u); }
__device__ __forceinline__ float leaky(float x) { return x >= 0.f ? x : 0.2f * x; }
__device__ __forceinline__ float sigmoidf(float x) { return 1.f / (1.f + __expf(-x)); }

// byte-level XOR swizzle (16B granular) keyed on row&7 — kills the 256/512B-stride bank conflicts
#define SWZ16(row, b) ((b) ^ (((row) & 7) << 4))

// ---------------- kernel 0: transpose + bf16 + pre-swizzle both W ----------------
// logical wT[m][c][k] = bf16(W_m[k][c]); stored with k ^ ((c&7)<<3) so that a LINEAR
// LDS copy + swizzled ds_read yields conflict-free B fragments.
__global__ __launch_bounds__(256) void prep_w(const float* __restrict__ wRef,
                                              const float* __restrict__ wDir,
                                              unsigned short* __restrict__ wT) {
    int i = blockIdx.x * 256 + threadIdx.x;      // 0..32767
    int m = i >> 14;
    int rr = i & 16383;
    int k = rr >> 7;
    int c = rr & 127;
    const float* W = m ? wDir : wRef;
    wT[m * 16384 + c * 128 + (k ^ (((c & 7) << 3)))] = f2bf(W[k * 128 + c]);
}

// ---------------- fused GEMM epilogue: Wh store + s,t row-dots ----------------
__device__ __forceinline__ void epilogue(const f32x4* acc, int rowBase, int w, int r, int g,
                                         int N, const float* __restrict__ aVec,
                                         unsigned short* __restrict__ wh,
                                         float* __restrict__ sArr, float* __restrict__ tArr) {
#pragma unroll
    for (int ct = 0; ct < 8; ++ct) {
#pragma unroll
        for (int q = 0; q < 4; ++q) {
            int row = rowBase + w * 16 + g * 4 + q;
            if (row < N) wh[(size_t)row * F + ct * 16 + r] = f2bf(acc[ct][q]);
        }
    }
    float ps[4] = {0.f, 0.f, 0.f, 0.f}, pt[4] = {0.f, 0.f, 0.f, 0.f};
#pragma unroll
    for (int ct = 0; ct < 8; ++ct) {
        int c = ct * 16 + r;
        float As = aVec[c], At = aVec[128 + c];
#pragma unroll
        for (int q = 0; q < 4; ++q) { ps[q] += acc[ct][q] * As; pt[q] += acc[ct][q] * At; }
    }
#pragma unroll
    for (int off = 1; off <= 8; off <<= 1) {
#pragma unroll
        for (int q = 0; q < 4; ++q) {
            ps[q] += __shfl_xor(ps[q], off);
            pt[q] += __shfl_xor(pt[q], off);
        }
    }
    if (r == 0) {
#pragma unroll
        for (int q = 0; q < 4; ++q) {
            int row = rowBase + w * 16 + g * 4 + q;
            if (row < N) { sArr[row] = ps[q]; tArr[row] = pt[q]; }
        }
    }
}

// ---------------- kernel 1: LDS-staged MFMA GEMM, both matrices, fused s/t ----------------
// block = 256 threads (4 waves) = 64 rows. LDS: A tile 32KB (f32, swizzled) + W 32KB (one matrix).
__global__ __launch_bounds__(256) void gemm_wh(const float* __restrict__ h,
                                               const unsigned short* __restrict__ wT,
                                               const float* __restrict__ aRefG,
                                               const float* __restrict__ aDirG,
                                               unsigned short* __restrict__ whRef,
                                               unsigned short* __restrict__ whDir,
                                               float* __restrict__ sRef, float* __restrict__ tRef,
                                               float* __restrict__ sDir, float* __restrict__ tDir,
                                               int N) {
    __shared__ unsigned char lds_a[32768];
    __shared__ unsigned char lds_w[32768];
    const int tid = threadIdx.x;
    const int lane = tid & 63, w = tid >> 6;
    const int r = lane & 15, g = lane >> 4;
    const int rowBase = blockIdx.x * 64;

    // ---- stage A (64 rows x 512B f32), swizzled via SOURCE address; LDS stays linear ----
#pragma unroll
    for (int it = 0; it < 8; ++it) {
        int lin = it * 4096 + tid * 16;
        int arow = lin >> 9, x = lin & 511;
        int grow = min(rowBase + arow, N - 1);
        uint4 v = *(const uint4*)((const char*)h + (size_t)grow * 512 + SWZ16(arow, x));
        *(uint4*)(lds_a + lin) = v;
    }
    // ---- stage W matrix 0 (already pre-swizzled in global) ----
#pragma unroll
    for (int it = 0; it < 8; ++it) {
        int lin = it * 4096 + tid * 16;
        *(uint4*)(lds_w + lin) = *(const uint4*)((const char*)wT + lin);
    }
    __syncthreads();

    // ---- A fragments (bf16, shared by both matrices) ----
    s16x8 afr[4];
    {
        const int arow = w * 16 + r;
#pragma unroll
        for (int kt = 0; kt < 4; ++kt) {
            int kb = kt * 128 + g * 32;
            float4 f0 = *(const float4*)(lds_a + arow * 512 + SWZ16(arow, kb));
            float4 f1 = *(const float4*)(lds_a + arow * 512 + SWZ16(arow, kb + 16));
            s16x8 a;
            a[0] = (short)f2bf(f0.x); a[1] = (short)f2bf(f0.y);
            a[2] = (short)f2bf(f0.z); a[3] = (short)f2bf(f0.w);
            a[4] = (short)f2bf(f1.x); a[5] = (short)f2bf(f1.y);
            a[6] = (short)f2bf(f1.z); a[7] = (short)f2bf(f1.w);
            afr[kt] = a;
        }
    }

    // ---- matrix 0 ----
    {
        f32x4 acc[8];
#pragma unroll
        for (int ct = 0; ct < 8; ++ct) acc[ct] = (f32x4){0.f, 0.f, 0.f, 0.f};
#pragma unroll
        for (int kt = 0; kt < 4; ++kt) {
#pragma unroll
            for (int ct = 0; ct < 8; ++ct) {
                int c = ct * 16 + r;
                s16x8 b = *(const s16x8*)(lds_w + c * 256 + SWZ16(c, kt * 64 + g * 16));
                acc[ct] = __builtin_amdgcn_mfma_f32_16x16x32_bf16(afr[kt], b, acc[ct], 0, 0, 0);
            }
        }
        epilogue(acc, rowBase, w, r, g, N, aRefG, whRef, sRef, tRef);
    }
    __syncthreads();
    // ---- stage W matrix 1 ----
#pragma unroll
    for (int it = 0; it < 8; ++it) {
        int lin = it * 4096 + tid * 16;
        *(uint4*)(lds_w + lin) = *(const uint4*)((const char*)wT + 32768 + lin);
    }
    __syncthreads();
    // ---- matrix 1 ----
    {
        f32x4 acc[8];
#pragma unroll
        for (int ct = 0; ct < 8; ++ct) acc[ct] = (f32x4){0.f, 0.f, 0.f, 0.f};
#pragma unroll
        for (int kt = 0; kt < 4; ++kt) {
#pragma unroll
            for (int ct = 0; ct < 8; ++ct) {
                int c = ct * 16 + r;
                s16x8 b = *(const s16x8*)(lds_w + c * 256 + SWZ16(c, kt * 64 + g * 16));
                acc[ct] = __builtin_amdgcn_mfma_f32_16x16x32_bf16(afr[kt], b, acc[ct], 0, 0, 0);
            }
        }
        epilogue(acc, rowBase, w, r, g, N, aDirG, whDir, sDir, tDir);
    }
}

// ---------------- kernel 2: gather + attention + output (one wave per node) ----------------
__device__ __forceinline__ void acc8(float* a, uint4 u, float c) {
    a[0] += c * bflo(u.x); a[1] += c * bfhi(u.x);
    a[2] += c * bflo(u.y); a[3] += c * bfhi(u.y);
    a[4] += c * bflo(u.z); a[5] += c * bfhi(u.z);
    a[6] += c * bflo(u.w); a[7] += c * bfhi(u.w);
}

__global__ __launch_bounds__(256) void gather_attn(
    const unsigned short* __restrict__ whRef, const unsigned short* __restrict__ whDir,
    const float* __restrict__ sRef, const float* __restrict__ tRef,
    const float* __restrict__ sDir, const float* __restrict__ tDir,
    const int* __restrict__ refNbr, const int* __restrict__ refCnt,
    const int* __restrict__ dirNbr, const int* __restrict__ dirCnt,
    float* __restrict__ out, int N) {
    __shared__ int2 s_list[4][72];   // [0..Lr) ref entries, [40..40+dcnt) dir entries

    const int wid = threadIdx.x >> 6;
    const int lane = threadIdx.x & 63;
    const int q = lane >> 4, hl16 = lane & 15;
    const int d = lane >> 4, kk = lane & 15;     // ref phase: 4 depth-groups of 16 lanes
    const int n_raw = blockIdx.x * 4 + wid;
    const int n = min(n_raw, N - 1);

    // ---- ref logits: lane (d,kk) owns slot kk of depth d ----
    int cnt = refCnt[n * 4 + d];
    bool validR = kk < cnt;
    int idxR = 0;
    float tv = 0.f;
    if (kk < 10) idxR = refNbr[(size_t)n * 40 + d * 10 + kk];
    if (validR) tv = tRef[idxR];
    float sum = tv;
    sum += __shfl_xor(sum, 1); sum += __shfl_xor(sum, 2);
    sum += __shfl_xor(sum, 4); sum += __shfl_xor(sum, 8);
    float rc = 1.f / (float)max(cnt, 1);
    float e = leaky(sRef[n] + sum * rc);
    float mx = fmaxf(e, __shfl_xor(e, 16)); mx = fmaxf(mx, __shfl_xor(mx, 32));
    float wgt = __expf(e - mx);
    float den = wgt + __shfl_xor(wgt, 16); den += __shfl_xor(den, 32);
    float coefR = wgt / den * rc;
    unsigned long long mask = __ballot(validR);
    int pos = (int)__popcll(mask & ((1ull << lane) - 1ull));
    int Lr = (int)__popcll(mask);
    if (validR) s_list[wid][pos] = make_int2(idxR, __float_as_int(coefR));

    // ---- dir logits: lanes 0..31 ----
    int dcnt = dirCnt[n];
    float eD = -1e30f;
    int idxD = 0;
    if (lane < 32) {
        idxD = dirNbr[(size_t)n * 32 + lane];
        if (lane < dcnt) eD = leaky(sDir[n] + tDir[idxD]);
    }
    float mD = eD;
#pragma unroll
    for (int off = 16; off; off >>= 1) mD = fmaxf(mD, __shfl_xor(mD, off, 32));
    float wD = (lane < dcnt) ? __expf(eD - mD) : 0.f;
    float dD = wD;
#pragma unroll
    for (int off = 16; off; off >>= 1) dD += __shfl_xor(dD, off, 32);
    if (lane < dcnt) s_list[wid][40 + lane] = make_int2(idxD, __float_as_int(wD / dD));

    __syncthreads();

    // ---- gather: quarter-wave per row, dwordx4/lane, 2-deep pipelined ----
    float accR[8] = {0.f, 0.f, 0.f, 0.f, 0.f, 0.f, 0.f, 0.f};
    {
        int nIt = (Lr + 3) >> 2;
        for (int t = 0; t < nIt; t += 2) {
            int e0 = 4 * t + q, e1 = e0 + 4;
            bool v0 = e0 < Lr, v1 = e1 < Lr;
            uint4 u0, u1; float c0 = 0.f, c1 = 0.f;
            if (v0) {
                int2 ic = s_list[wid][e0];
                c0 = __int_as_float(ic.y);
                u0 = *(const uint4*)((const char*)whRef + ((size_t)(unsigned)ic.x << 8) + (hl16 << 4));
            }
            if (v1) {
                int2 ic = s_list[wid][e1];
                c1 = __int_as_float(ic.y);
                u1 = *(const uint4*)((const char*)whRef + ((size_t)(unsigned)ic.x << 8) + (hl16 << 4));
            }
            if (v0) acc8(accR, u0, c0);
            if (v1) acc8(accR, u1, c1);
        }
    }
    float accD[8] = {0.f, 0.f, 0.f, 0.f, 0.f, 0.f, 0.f, 0.f};
    {
        int nIt = (dcnt + 3) >> 2;
        for (int t = 0; t < nIt; t += 2) {
            int e0 = 4 * t + q, e1 = e0 + 4;
            bool v0 = e0 < dcnt, v1 = e1 < dcnt;
            uint4 u0, u1; float c0 = 0.f, c1 = 0.f;
            if (v0) {
                int2 ic = s_list[wid][40 + e0];
                c0 = __int_as_float(ic.y);
                u0 = *(const uint4*)((const char*)whDir + ((size_t)(unsigned)ic.x << 8) + (hl16 << 4));
            }
            if (v1) {
                int2 ic = s_list[wid][40 + e1];
                c1 = __int_as_float(ic.y);
                u1 = *(const uint4*)((const char*)whDir + ((size_t)(unsigned)ic.x << 8) + (hl16 << 4));
            }
            if (v0) acc8(accD, u0, c0);
            if (v1) acc8(accD, u1, c1);
        }
    }

    // ---- combine quarters + write ----
#pragma unroll
    for (int j = 0; j < 8; ++j) {
        accR[j] += __shfl_xor(accR[j], 16); accR[j] += __shfl_xor(accR[j], 32);
        accD[j] += __shfl_xor(accD[j], 16); accD[j] += __shfl_xor(accD[j], 32);
    }
    if (n_raw < N && q == 0) {
        float o[8];
#pragma unroll
        for (int j = 0; j < 8; ++j) o[j] = 0.5f * (sigmoidf(accR[j]) + sigmoidf(accD[j]));
        float4* dst = (float4*)(out + (size_t)n * F + hl16 * 8);
        dst[0] = make_float4(o[0], o[1], o[2], o[3]);
        dst[1] = make_float4(o[4], o[5], o[6], o[7]);
    }
}

extern "C" void kernel_launch(void* const* d_in, const int* in_sizes, int n_in,
                              void* d_out, int out_size, void* d_ws, size_t ws_size,
                              hipStream_t stream) {
    const float* h    = (const float*)d_in[0];
    const float* Wref = (const float*)d_in[1];
    const float* aRef = (const float*)d_in[2];
    const float* Wdir = (const float*)d_in[3];
    const float* aDir = (const float*)d_in[4];
    const int* refNbr = (const int*)d_in[5];
    const int* refCnt = (const int*)d_in[6];
    const int* dirNbr = (const int*)d_in[7];
    const int* dirCnt = (const int*)d_in[8];
    float* out = (float*)d_out;
    const int N = in_sizes[0] / F;

    const size_t NF = (size_t)N * F;
    unsigned short* whRef = (unsigned short*)d_ws;          // NF bf16
    unsigned short* whDir = whRef + NF;                     // NF bf16
    float* sRef = (float*)(whDir + NF);
    float* tRef = sRef + N;
    float* sDir = tRef + N;
    float* tDir = sDir + N;
    unsigned short* wT = (unsigned short*)(tDir + N);       // 2*128*128 bf16, pre-swizzled

    prep_w<<<128, 256, 0, stream>>>(Wref, Wdir, wT);
    gemm_wh<<<(N + 63) / 64, 256, 0, stream>>>(h, wT, aRef, aDir, whRef, whDir,
                                               sRef, tRef, sDir, tDir, N);
    gather_attn<<<(N + 3) / 4, 256, 0, stream>>>(whRef, whDir, sRef, tRef, sDir, tDir,
                                                 refNbr, refCnt, dirNbr, dirCnt, out, N);
}

// Round 4
// 291.093 us; speedup vs baseline: 1.3213x; 1.0590x over previous
//
#include <hip/hip_runtime.h>

typedef __attribute__((ext_vector_type(8))) short s16x8;
typedef __attribute__((ext_vector_type(4))) float f32x4;

#define F 128

__device__ __forceinline__ unsigned short f2bf(float f) {
    unsigned int u = __float_as_uint(f);
    u = (u + 0x7fffu + ((u >> 16) & 1u)) >> 16;
    return (unsigned short)u;
}
__device__ __forceinline__ float bflo(unsigned int u) { return __uint_as_float(u << 16); }
__device__ __forceinline__ float bfhi(unsigned int u) { return __uint_as_float(u & 0xffff0000u); }
__device__ __forceinline__ float leaky(float x) { return x >= 0.f ? x : 0.2f * x; }
__device__ __forceinline__ float sigmoidf(float x) { return 1.f / (1.f + __expf(-x)); }

// byte-level XOR swizzle (16B granular within a 128B stripe), keyed on row&7
#define SWZ16(row, b) ((b) ^ (((row) & 7) << 4))

// async global->LDS, 16B per lane. dst must be wave-uniform base + lane*16 (it is).
__device__ __forceinline__ void glds16(void* lds, const void* g) {
    __builtin_amdgcn_global_load_lds(
        (const __attribute__((address_space(1))) unsigned int*)g,
        (__attribute__((address_space(3))) unsigned int*)lds,
        16, 0, 0);
}

// ---------------- kernel 0: transpose + bf16 + pre-swizzle both W ----------------
// logical wT[m][c][k] = bf16(W_m[k][c]); stored with k ^ ((c&7)<<3) (element-level)
// == byte-level SWZ16(c, 2k), so a LINEAR LDS copy + swizzled ds_read is conflict-light.
__global__ __launch_bounds__(256) void prep_w(const float* __restrict__ wRef,
                                              const float* __restrict__ wDir,
                                              unsigned short* __restrict__ wT) {
    int i = blockIdx.x * 256 + threadIdx.x;      // 0..32767
    int m = i >> 14;
    int rr = i & 16383;
    int k = rr >> 7;
    int c = rr & 127;
    const float* W = m ? wDir : wRef;
    wT[m * 16384 + c * 128 + (k ^ (((c & 7) << 3)))] = f2bf(W[k * 128 + c]);
}

// ---------------- fused epilogue: s/t row-dots + C through wave-local LDS ----------------
__device__ __forceinline__ void epi(const f32x4* acc, unsigned char* cb /*wave-local 4KB*/,
                                    int rowBase, int w, int r, int g, int lane, int N,
                                    const float* __restrict__ aVec,
                                    unsigned short* __restrict__ wh,
                                    float* __restrict__ sArr, float* __restrict__ tArr) {
    // ---- s/t dots on registers ----
    float ps[4] = {0.f, 0.f, 0.f, 0.f}, pt[4] = {0.f, 0.f, 0.f, 0.f};
#pragma unroll
    for (int ct = 0; ct < 8; ++ct) {
        int c = ct * 16 + r;
        float As = aVec[c], At = aVec[128 + c];
#pragma unroll
        for (int q = 0; q < 4; ++q) { ps[q] += acc[ct][q] * As; pt[q] += acc[ct][q] * At; }
    }
#pragma unroll
    for (int off = 1; off <= 8; off <<= 1) {
#pragma unroll
        for (int q = 0; q < 4; ++q) {
            ps[q] += __shfl_xor(ps[q], off);
            pt[q] += __shfl_xor(pt[q], off);
        }
    }
    if (r == 0) {
#pragma unroll
        for (int q = 0; q < 4; ++q) {
            int row = rowBase + w * 16 + g * 4 + q;
            if (row < N) { sArr[row] = ps[q]; tArr[row] = pt[q]; }
        }
    }
    // ---- C -> wave-local LDS (bf16, swizzled) ----
#pragma unroll
    for (int ct = 0; ct < 8; ++ct) {
#pragma unroll
        for (int q = 0; q < 4; ++q) {
            int lrow = g * 4 + q;                       // 0..15 within wave tile
            int xb = (ct * 16 + r) * 2;                 // byte col
            *(unsigned short*)(cb + lrow * 256 + SWZ16(lrow, xb)) = f2bf(acc[ct][q]);
        }
    }
    // ---- read back linear + coalesced dwordx4 stores (wave-local; waitcnt orders) ----
#pragma unroll
    for (int i = 0; i < 4; ++i) {
        int off = i * 1024 + lane * 16;                 // 4KB / 64 lanes = 64B each
        int lrow = off >> 8, x = off & 255;
        uint4 v = *(const uint4*)(cb + lrow * 256 + SWZ16(lrow, x));
        int grow = rowBase + w * 16 + lrow;
        if (grow < N) *(uint4*)((char*)wh + (size_t)grow * 256 + x) = v;
    }
}

// ---------------- kernel 1: gll-staged MFMA GEMM, both matrices, fused s/t ----------------
// 256 thr (4 waves) = 64 rows. LDS: A f32 32KB (wave-local 8KB regions) + W phase 32KB.
__global__ __launch_bounds__(256) void gemm_wh(const float* __restrict__ h,
                                               const unsigned short* __restrict__ wT,
                                               const float* __restrict__ aRefG,
                                               const float* __restrict__ aDirG,
                                               unsigned short* __restrict__ whRef,
                                               unsigned short* __restrict__ whDir,
                                               float* __restrict__ sRef, float* __restrict__ tRef,
                                               float* __restrict__ sDir, float* __restrict__ tDir,
                                               int N) {
    __shared__ unsigned char lds[65536];
    const int tid = threadIdx.x;
    const int lane = tid & 63, w = tid >> 6;
    const int r = lane & 15, g = lane >> 4;
    const int rowBase = blockIdx.x * 64;

    // ---- stage A (64 rows x 512B f32, source-swizzled) + W0, all via global_load_lds ----
#pragma unroll
    for (int it = 0; it < 8; ++it) {
        int lin = it * 4096 + tid * 16;
        int arow = lin >> 9, x = lin & 511;
        int grow = min(rowBase + arow, N - 1);
        glds16(lds + lin, (const char*)h + (size_t)grow * 512 + SWZ16(arow, x));
    }
#pragma unroll
    for (int it = 0; it < 8; ++it) {
        int lin = it * 4096 + tid * 16;
        glds16(lds + 32768 + lin, (const char*)wT + lin);
    }
    __syncthreads();

    // ---- A fragments (f32 -> bf16), wave-local region ----
    s16x8 afr[4];
    {
        const int arow = w * 16 + r;
#pragma unroll
        for (int kt = 0; kt < 4; ++kt) {
            int kb = kt * 128 + g * 32;
            float4 f0 = *(const float4*)(lds + arow * 512 + SWZ16(arow, kb));
            float4 f1 = *(const float4*)(lds + arow * 512 + SWZ16(arow, kb + 16));
            s16x8 a;
            a[0] = (short)f2bf(f0.x); a[1] = (short)f2bf(f0.y);
            a[2] = (short)f2bf(f0.z); a[3] = (short)f2bf(f0.w);
            a[4] = (short)f2bf(f1.x); a[5] = (short)f2bf(f1.y);
            a[6] = (short)f2bf(f1.z); a[7] = (short)f2bf(f1.w);
            afr[kt] = a;
        }
    }
    unsigned char* cb = lds + w * 8192;   // wave-local 4KB C-buffer (A region, frags consumed)

    // ---- matrix 0 ----
    {
        f32x4 acc[8];
#pragma unroll
        for (int ct = 0; ct < 8; ++ct) acc[ct] = (f32x4){0.f, 0.f, 0.f, 0.f};
#pragma unroll
        for (int kt = 0; kt < 4; ++kt) {
#pragma unroll
            for (int ct = 0; ct < 8; ++ct) {
                int c = ct * 16 + r;
                s16x8 b = *(const s16x8*)(lds + 32768 + c * 256 + SWZ16(c, kt * 64 + g * 16));
                acc[ct] = __builtin_amdgcn_mfma_f32_16x16x32_bf16(afr[kt], b, acc[ct], 0, 0, 0);
            }
        }
        epi(acc, cb, rowBase, w, r, g, lane, N, aRefG, whRef, sRef, tRef);
    }
    __syncthreads();                       // all waves done with W0
#pragma unroll
    for (int it = 0; it < 8; ++it) {       // stage W1
        int lin = it * 4096 + tid * 16;
        glds16(lds + 32768 + lin, (const char*)wT + 32768 + lin);
    }
    __syncthreads();
    // ---- matrix 1 ----
    {
        f32x4 acc[8];
#pragma unroll
        for (int ct = 0; ct < 8; ++ct) acc[ct] = (f32x4){0.f, 0.f, 0.f, 0.f};
#pragma unroll
        for (int kt = 0; kt < 4; ++kt) {
#pragma unroll
            for (int ct = 0; ct < 8; ++ct) {
                int c = ct * 16 + r;
                s16x8 b = *(const s16x8*)(lds + 32768 + c * 256 + SWZ16(c, kt * 64 + g * 16));
                acc[ct] = __builtin_amdgcn_mfma_f32_16x16x32_bf16(afr[kt], b, acc[ct], 0, 0, 0);
            }
        }
        epi(acc, cb, rowBase, w, r, g, lane, N, aDirG, whDir, sDir, tDir);
    }
}

// ---------------- kernel 2: gather + attention + output (one wave per node) ----------------
__device__ __forceinline__ void acc8(float* a, uint4 u, float c) {
    a[0] += c * bflo(u.x); a[1] += c * bfhi(u.x);
    a[2] += c * bflo(u.y); a[3] += c * bfhi(u.y);
    a[4] += c * bflo(u.z); a[5] += c * bfhi(u.z);
    a[6] += c * bflo(u.w); a[7] += c * bfhi(u.w);
}

__global__ __launch_bounds__(256) void gather_attn(
    const unsigned short* __restrict__ whRef, const unsigned short* __restrict__ whDir,
    const float* __restrict__ sRef, const float* __restrict__ tRef,
    const float* __restrict__ sDir, const float* __restrict__ tDir,
    const int* __restrict__ refNbr, const int* __restrict__ refCnt,
    const int* __restrict__ dirNbr, const int* __restrict__ dirCnt,
    float* __restrict__ out, int N) {
    __shared__ int2 s_list[4][72];   // [0..Lr) ref entries, [40..40+dcnt) dir entries

    const int wid = threadIdx.x >> 6;
    const int lane = threadIdx.x & 63;
    const int q = lane >> 4, hl16 = lane & 15;
    const int d = lane >> 4, kk = lane & 15;     // ref phase: 4 depth-groups of 16 lanes
    const int n_raw = blockIdx.x * 4 + wid;
    const int n = min(n_raw, N - 1);

    // ---- ref logits: lane (d,kk) owns slot kk of depth d ----
    int cnt = refCnt[n * 4 + d];
    bool validR = kk < cnt;
    int idxR = 0;
    float tv = 0.f;
    if (kk < 10) idxR = refNbr[(size_t)n * 40 + d * 10 + kk];
    if (validR) tv = tRef[idxR];
    float sum = tv;
    sum += __shfl_xor(sum, 1); sum += __shfl_xor(sum, 2);
    sum += __shfl_xor(sum, 4); sum += __shfl_xor(sum, 8);
    float rc = 1.f / (float)max(cnt, 1);
    float e = leaky(sRef[n] + sum * rc);
    float mx = fmaxf(e, __shfl_xor(e, 16)); mx = fmaxf(mx, __shfl_xor(mx, 32));
    float wgt = __expf(e - mx);
    float den = wgt + __shfl_xor(wgt, 16); den += __shfl_xor(den, 32);
    float coefR = wgt / den * rc;
    unsigned long long mask = __ballot(validR);
    int pos = (int)__popcll(mask & ((1ull << lane) - 1ull));
    int Lr = (int)__popcll(mask);
    if (validR) s_list[wid][pos] = make_int2(idxR, __float_as_int(coefR));

    // ---- dir logits: lanes 0..31 ----
    int dcnt = dirCnt[n];
    float eD = -1e30f;
    int idxD = 0;
    if (lane < 32) {
        idxD = dirNbr[(size_t)n * 32 + lane];
        if (lane < dcnt) eD = leaky(sDir[n] + tDir[idxD]);
    }
    float mD = eD;
#pragma unroll
    for (int off = 16; off; off >>= 1) mD = fmaxf(mD, __shfl_xor(mD, off, 32));
    float wD = (lane < dcnt) ? __expf(eD - mD) : 0.f;
    float dD = wD;
#pragma unroll
    for (int off = 16; off; off >>= 1) dD += __shfl_xor(dD, off, 32);
    if (lane < dcnt) s_list[wid][40 + lane] = make_int2(idxD, __float_as_int(wD / dD));

    __syncthreads();

    // ---- ref gather: quarter-wave per row, ALL loads issued before any use (MLP~10) ----
    float accR[8] = {0.f, 0.f, 0.f, 0.f, 0.f, 0.f, 0.f, 0.f};
    {
        uint4 u[10]; float c[10];
#pragma unroll
        for (int j = 0; j < 10; ++j) {
            int e = j * 4 + q;
            if (e < Lr) {
                int2 ic = s_list[wid][e];
                c[j] = __int_as_float(ic.y);
                u[j] = *(const uint4*)((const char*)whRef + ((size_t)(unsigned)ic.x << 8) + (hl16 << 4));
            }
        }
#pragma unroll
        for (int j = 0; j < 10; ++j) {
            int e = j * 4 + q;
            if (e < Lr) acc8(accR, u[j], c[j]);
        }
    }
    // ---- dir gather: same pattern (MLP~8) ----
    float accD[8] = {0.f, 0.f, 0.f, 0.f, 0.f, 0.f, 0.f, 0.f};
    {
        uint4 u[8]; float c[8];
#pragma unroll
        for (int j = 0; j < 8; ++j) {
            int e = j * 4 + q;
            if (e < dcnt) {
                int2 ic = s_list[wid][40 + e];
                c[j] = __int_as_float(ic.y);
                u[j] = *(const uint4*)((const char*)whDir + ((size_t)(unsigned)ic.x << 8) + (hl16 << 4));
            }
        }
#pragma unroll
        for (int j = 0; j < 8; ++j) {
            int e = j * 4 + q;
            if (e < dcnt) acc8(accD, u[j], c[j]);
        }
    }

    // ---- combine quarters + write ----
#pragma unroll
    for (int j = 0; j < 8; ++j) {
        accR[j] += __shfl_xor(accR[j], 16); accR[j] += __shfl_xor(accR[j], 32);
        accD[j] += __shfl_xor(accD[j], 16); accD[j] += __shfl_xor(accD[j], 32);
    }
    if (n_raw < N && q == 0) {
        float o[8];
#pragma unroll
        for (int j = 0; j < 8; ++j) o[j] = 0.5f * (sigmoidf(accR[j]) + sigmoidf(accD[j]));
        float4* dst = (float4*)(out + (size_t)n * F + hl16 * 8);
        dst[0] = make_float4(o[0], o[1], o[2], o[3]);
        dst[1] = make_float4(o[4], o[5], o[6], o[7]);
    }
}

extern "C" void kernel_launch(void* const* d_in, const int* in_sizes, int n_in,
                              void* d_out, int out_size, void* d_ws, size_t ws_size,
                              hipStream_t stream) {
    const float* h    = (const float*)d_in[0];
    const float* Wref = (const float*)d_in[1];
    const float* aRef = (const float*)d_in[2];
    const float* Wdir = (const float*)d_in[3];
    const float* aDir = (const float*)d_in[4];
    const int* refNbr = (const int*)d_in[5];
    const int* refCnt = (const int*)d_in[6];
    const int* dirNbr = (const int*)d_in[7];
    const int* dirCnt = (const int*)d_in[8];
    float* out = (float*)d_out;
    const int N = in_sizes[0] / F;

    const size_t NF = (size_t)N * F;
    unsigned short* whRef = (unsigned short*)d_ws;          // NF bf16
    unsigned short* whDir = whRef + NF;                     // NF bf16
    float* sRef = (float*)(whDir + NF);
    float* tRef = sRef + N;
    float* sDir = tRef + N;
    float* tDir = sDir + N;
    unsigned short* wT = (unsigned short*)(tDir + N);       // 2*128*128 bf16, pre-swizzled

    prep_w<<<128, 256, 0, stream>>>(Wref, Wdir, wT);
    gemm_wh<<<(N + 63) / 64, 256, 0, stream>>>(h, wT, aRef, aDir, whRef, whDir,
                                               sRef, tRef, sDir, tDir, N);
    gather_attn<<<(N + 3) / 4, 256, 0, stream>>>(whRef, whDir, sRef, tRef, sDir, tDir,
                                                 refNbr, refCnt, dirNbr, dirCnt, out, N);
}

// Round 5
// 256.158 us; speedup vs baseline: 1.5016x; 1.1364x over previous
//
#include <hip/hip_runtime.h>

typedef __attribute__((ext_vector_type(8))) short s16x8;
typedef __attribute__((ext_vector_type(4))) float f32x4;
typedef __attribute__((ext_vector_type(2))) float f32x2;

#define F 128

__device__ __forceinline__ unsigned short f2bf(float f) {
    unsigned int u = __float_as_uint(f);
    u = (u + 0x7fffu + ((u >> 16) & 1u)) >> 16;
    return (unsigned short)u;
}
__device__ __forceinline__ float bflo(unsigned int u) { return __uint_as_float(u << 16); }
__device__ __forceinline__ float bfhi(unsigned int u) { return __uint_as_float(u & 0xffff0000u); }
__device__ __forceinline__ float leaky(float x) { return x >= 0.f ? x : 0.2f * x; }
__device__ __forceinline__ float sigmoidf(float x) { return 1.f / (1.f + __expf(-x)); }

// byte-level XOR swizzle (16B granular within a 128B stripe), keyed on row&7
#define SWZ16(row, b) ((b) ^ (((row) & 7) << 4))

// async global->LDS, 16B per lane (wave-uniform LDS base + lane*16)
__device__ __forceinline__ void glds16(void* lds, const void* g) {
    __builtin_amdgcn_global_load_lds(
        (const __attribute__((address_space(1))) unsigned int*)g,
        (__attribute__((address_space(3))) unsigned int*)lds,
        16, 0, 0);
}

// ---------------- kernel 0: transpose + bf16 + pre-swizzle both W ----------------
__global__ __launch_bounds__(256) void prep_w(const float* __restrict__ wRef,
                                              const float* __restrict__ wDir,
                                              unsigned short* __restrict__ wT) {
    int i = blockIdx.x * 256 + threadIdx.x;      // 0..32767
    int m = i >> 14;
    int rr = i & 16383;
    int k = rr >> 7;
    int c = rr & 127;
    const float* W = m ? wDir : wRef;
    wT[m * 16384 + c * 128 + (k ^ (((c & 7) << 3)))] = f2bf(W[k * 128 + c]);
}

// ---------------- fused epilogue: s/t row-dots (f32) + C -> fp8 via wave-local LDS ----------------
__device__ __forceinline__ void epi(const f32x4* acc, unsigned char* cb /*wave-local 4KB bf16*/,
                                    int rowBase, int w, int r, int g, int lane, int N,
                                    const float* __restrict__ aVec,
                                    unsigned char* __restrict__ wh /*fp8, 128B rows*/,
                                    float* __restrict__ sArr, float* __restrict__ tArr) {
    // ---- s/t dots on f32 accumulators (full precision logits) ----
    float ps[4] = {0.f, 0.f, 0.f, 0.f}, pt[4] = {0.f, 0.f, 0.f, 0.f};
#pragma unroll
    for (int ct = 0; ct < 8; ++ct) {
        int c = ct * 16 + r;
        float As = aVec[c], At = aVec[128 + c];
#pragma unroll
        for (int q = 0; q < 4; ++q) { ps[q] += acc[ct][q] * As; pt[q] += acc[ct][q] * At; }
    }
#pragma unroll
    for (int off = 1; off <= 8; off <<= 1) {
#pragma unroll
        for (int q = 0; q < 4; ++q) {
            ps[q] += __shfl_xor(ps[q], off);
            pt[q] += __shfl_xor(pt[q], off);
        }
    }
    if (r == 0) {
#pragma unroll
        for (int q = 0; q < 4; ++q) {
            int row = rowBase + w * 16 + g * 4 + q;
            if (row < N) { sArr[row] = ps[q]; tArr[row] = pt[q]; }
        }
    }
    // ---- C -> wave-local LDS (bf16, swizzled) ----
#pragma unroll
    for (int ct = 0; ct < 8; ++ct) {
#pragma unroll
        for (int q = 0; q < 4; ++q) {
            int lrow = g * 4 + q;                       // 0..15 within wave tile
            int xb = (ct * 16 + r) * 2;                 // byte col in bf16 row
            *(unsigned short*)(cb + lrow * 256 + SWZ16(lrow, xb)) = f2bf(acc[ct][q]);
        }
    }
    // ---- read back linear (deswizzled) -> fp8 pack -> coalesced 8B stores ----
#pragma unroll
    for (int i = 0; i < 4; ++i) {
        int off = i * 1024 + lane * 16;                 // byte in bf16 tile (4KB/wave)
        int lrow = off >> 8, x = off & 255;             // x: bf16 byte col, 16B granule
        uint4 v = *(const uint4*)(cb + lrow * 256 + SWZ16(lrow, x));
        int pk0 = __builtin_amdgcn_cvt_pk_fp8_f32(bflo(v.x), bfhi(v.x), 0, false);
        pk0 = __builtin_amdgcn_cvt_pk_fp8_f32(bflo(v.y), bfhi(v.y), pk0, true);
        int pk1 = __builtin_amdgcn_cvt_pk_fp8_f32(bflo(v.z), bfhi(v.z), 0, false);
        pk1 = __builtin_amdgcn_cvt_pk_fp8_f32(bflo(v.w), bfhi(v.w), pk1, true);
        int grow = rowBase + w * 16 + lrow;
        if (grow < N) *(uint2*)(wh + (size_t)grow * 128 + (x >> 1)) = make_uint2((unsigned)pk0, (unsigned)pk1);
    }
}

// ---------------- kernel 1: MFMA GEMM, both matrices, fused s/t + fp8 Wh ----------------
// 256 thr (4 waves) = 64 rows. LDS 48KB: A/C bf16 16KB (wave-local 4KB) + W 32KB.
__global__ __launch_bounds__(256) void gemm_wh(const float* __restrict__ h,
                                               const unsigned short* __restrict__ wT,
                                               const float* __restrict__ aRefG,
                                               const float* __restrict__ aDirG,
                                               unsigned char* __restrict__ whRef,
                                               unsigned char* __restrict__ whDir,
                                               float* __restrict__ sRef, float* __restrict__ tRef,
                                               float* __restrict__ sDir, float* __restrict__ tDir,
                                               int N) {
    __shared__ unsigned char lds[49152];
    const int tid = threadIdx.x;
    const int lane = tid & 63, w = tid >> 6;
    const int r = lane & 15, g = lane >> 4;
    const int rowBase = blockIdx.x * 64;

    // ---- issue W0 async staging (global_load_lds, pre-swizzled source) ----
#pragma unroll
    for (int it = 0; it < 8; ++it) {
        int lin = it * 4096 + tid * 16;
        glds16(lds + 16384 + lin, (const char*)wT + lin);
    }
    // ---- reg-stage A: f32 global -> bf16 LDS (swizzled), 4 iters x 16B ----
    float4 av[4][2];
#pragma unroll
    for (int it = 0; it < 4; ++it) {
        int lin = it * 4096 + tid * 16;                 // byte in bf16 tile
        int arow = lin >> 8, x = lin & 255;
        int grow = min(rowBase + arow, N - 1);
        const char* src = (const char*)h + (size_t)grow * 512 + x * 2;
        av[it][0] = *(const float4*)(src);
        av[it][1] = *(const float4*)(src + 16);
    }
#pragma unroll
    for (int it = 0; it < 4; ++it) {
        int lin = it * 4096 + tid * 16;
        int arow = lin >> 8, x = lin & 255;
        s16x8 a;
        a[0] = (short)f2bf(av[it][0].x); a[1] = (short)f2bf(av[it][0].y);
        a[2] = (short)f2bf(av[it][0].z); a[3] = (short)f2bf(av[it][0].w);
        a[4] = (short)f2bf(av[it][1].x); a[5] = (short)f2bf(av[it][1].y);
        a[6] = (short)f2bf(av[it][1].z); a[7] = (short)f2bf(av[it][1].w);
        *(s16x8*)(lds + arow * 256 + SWZ16(arow, x)) = a;
    }
    __syncthreads();

    // ---- A fragments from wave-local rows (already bf16) ----
    s16x8 afr[4];
    {
        const int arow = w * 16 + r;
#pragma unroll
        for (int kt = 0; kt < 4; ++kt)
            afr[kt] = *(const s16x8*)(lds + arow * 256 + SWZ16(arow, kt * 64 + g * 16));
    }
    unsigned char* cb = lds + w * 4096;   // wave-local 4KB C-buffer (reuses A rows, wave-local)

    // ---- matrix 0 ----
    {
        f32x4 acc[8];
#pragma unroll
        for (int ct = 0; ct < 8; ++ct) acc[ct] = (f32x4){0.f, 0.f, 0.f, 0.f};
#pragma unroll
        for (int kt = 0; kt < 4; ++kt) {
#pragma unroll
            for (int ct = 0; ct < 8; ++ct) {
                int c = ct * 16 + r;
                s16x8 b = *(const s16x8*)(lds + 16384 + c * 256 + SWZ16(c, kt * 64 + g * 16));
                acc[ct] = __builtin_amdgcn_mfma_f32_16x16x32_bf16(afr[kt], b, acc[ct], 0, 0, 0);
            }
        }
        epi(acc, cb, rowBase, w, r, g, lane, N, aRefG, whRef, sRef, tRef);
    }
    __syncthreads();                       // all waves done with W0
#pragma unroll
    for (int it = 0; it < 8; ++it) {       // stage W1
        int lin = it * 4096 + tid * 16;
        glds16(lds + 16384 + lin, (const char*)wT + 32768 + lin);
    }
    __syncthreads();
    // ---- matrix 1 ----
    {
        f32x4 acc[8];
#pragma unroll
        for (int ct = 0; ct < 8; ++ct) acc[ct] = (f32x4){0.f, 0.f, 0.f, 0.f};
#pragma unroll
        for (int kt = 0; kt < 4; ++kt) {
#pragma unroll
            for (int ct = 0; ct < 8; ++ct) {
                int c = ct * 16 + r;
                s16x8 b = *(const s16x8*)(lds + 16384 + c * 256 + SWZ16(c, kt * 64 + g * 16));
                acc[ct] = __builtin_amdgcn_mfma_f32_16x16x32_bf16(afr[kt], b, acc[ct], 0, 0, 0);
            }
        }
        epi(acc, cb, rowBase, w, r, g, lane, N, aDirG, whDir, sDir, tDir);
    }
}

// ---------------- kernel 2: gather + attention + output (one wave per node, fp8 rows) ----------------
__device__ __forceinline__ void acc8f8(float* a, uint2 u, float c) {
    f32x2 p0 = __builtin_amdgcn_cvt_pk_f32_fp8((int)u.x, false);
    f32x2 p1 = __builtin_amdgcn_cvt_pk_f32_fp8((int)u.x, true);
    f32x2 p2 = __builtin_amdgcn_cvt_pk_f32_fp8((int)u.y, false);
    f32x2 p3 = __builtin_amdgcn_cvt_pk_f32_fp8((int)u.y, true);
    a[0] += c * p0[0]; a[1] += c * p0[1];
    a[2] += c * p1[0]; a[3] += c * p1[1];
    a[4] += c * p2[0]; a[5] += c * p2[1];
    a[6] += c * p3[0]; a[7] += c * p3[1];
}

__global__ __launch_bounds__(256) void gather_attn(
    const unsigned char* __restrict__ whRef, const unsigned char* __restrict__ whDir,
    const float* __restrict__ sRef, const float* __restrict__ tRef,
    const float* __restrict__ sDir, const float* __restrict__ tDir,
    const int* __restrict__ refNbr, const int* __restrict__ refCnt,
    const int* __restrict__ dirNbr, const int* __restrict__ dirCnt,
    float* __restrict__ out, int N) {
    __shared__ int2 s_list[4][72];   // [0..Lr) ref entries, [40..40+dcnt) dir entries

    const int wid = threadIdx.x >> 6;
    const int lane = threadIdx.x & 63;
    const int q = lane >> 4, hl16 = lane & 15;
    const int d = lane >> 4, kk = lane & 15;     // ref phase: 4 depth-groups of 16 lanes
    const int n_raw = blockIdx.x * 4 + wid;
    const int n = min(n_raw, N - 1);

    // ---- ref logits: lane (d,kk) owns slot kk of depth d ----
    int cnt = refCnt[n * 4 + d];
    bool validR = kk < cnt;
    int idxR = 0;
    float tv = 0.f;
    if (kk < 10) idxR = refNbr[(size_t)n * 40 + d * 10 + kk];
    if (validR) tv = tRef[idxR];
    float sum = tv;
    sum += __shfl_xor(sum, 1); sum += __shfl_xor(sum, 2);
    sum += __shfl_xor(sum, 4); sum += __shfl_xor(sum, 8);
    float rc = 1.f / (float)max(cnt, 1);
    float e = leaky(sRef[n] + sum * rc);
    float mx = fmaxf(e, __shfl_xor(e, 16)); mx = fmaxf(mx, __shfl_xor(mx, 32));
    float wgt = __expf(e - mx);
    float den = wgt + __shfl_xor(wgt, 16); den += __shfl_xor(den, 32);
    float coefR = wgt / den * rc;
    unsigned long long mask = __ballot(validR);
    int pos = (int)__popcll(mask & ((1ull << lane) - 1ull));
    int Lr = (int)__popcll(mask);
    if (validR) s_list[wid][pos] = make_int2(idxR, __float_as_int(coefR));

    // ---- dir logits: lanes 0..31 ----
    int dcnt = dirCnt[n];
    float eD = -1e30f;
    int idxD = 0;
    if (lane < 32) {
        idxD = dirNbr[(size_t)n * 32 + lane];
        if (lane < dcnt) eD = leaky(sDir[n] + tDir[idxD]);
    }
    float mD = eD;
#pragma unroll
    for (int off = 16; off; off >>= 1) mD = fmaxf(mD, __shfl_xor(mD, off, 32));
    float wD = (lane < dcnt) ? __expf(eD - mD) : 0.f;
    float dD = wD;
#pragma unroll
    for (int off = 16; off; off >>= 1) dD += __shfl_xor(dD, off, 32);
    if (lane < dcnt) s_list[wid][40 + lane] = make_int2(idxD, __float_as_int(wD / dD));

    __syncthreads();

    // ---- ref gather: quarter-wave per row (16 lanes x 8B = 128B), all loads first ----
    float accR[8] = {0.f, 0.f, 0.f, 0.f, 0.f, 0.f, 0.f, 0.f};
    {
        uint2 u[10]; float c[10];
#pragma unroll
        for (int j = 0; j < 10; ++j) {
            int e = j * 4 + q;
            if (e < Lr) {
                int2 ic = s_list[wid][e];
                c[j] = __int_as_float(ic.y);
                u[j] = *(const uint2*)(whRef + ((size_t)(unsigned)ic.x << 7) + (hl16 << 3));
            }
        }
#pragma unroll
        for (int j = 0; j < 10; ++j) {
            int e = j * 4 + q;
            if (e < Lr) acc8f8(accR, u[j], c[j]);
        }
    }
    // ---- dir gather ----
    float accD[8] = {0.f, 0.f, 0.f, 0.f, 0.f, 0.f, 0.f, 0.f};
    {
        uint2 u[8]; float c[8];
#pragma unroll
        for (int j = 0; j < 8; ++j) {
            int e = j * 4 + q;
            if (e < dcnt) {
                int2 ic = s_list[wid][40 + e];
                c[j] = __int_as_float(ic.y);
                u[j] = *(const uint2*)(whDir + ((size_t)(unsigned)ic.x << 7) + (hl16 << 3));
            }
        }
#pragma unroll
        for (int j = 0; j < 8; ++j) {
            int e = j * 4 + q;
            if (e < dcnt) acc8f8(accD, u[j], c[j]);
        }
    }

    // ---- combine quarters + write ----
#pragma unroll
    for (int j = 0; j < 8; ++j) {
        accR[j] += __shfl_xor(accR[j], 16); accR[j] += __shfl_xor(accR[j], 32);
        accD[j] += __shfl_xor(accD[j], 16); accD[j] += __shfl_xor(accD[j], 32);
    }
    if (n_raw < N && q == 0) {
        float o[8];
#pragma unroll
        for (int j = 0; j < 8; ++j) o[j] = 0.5f * (sigmoidf(accR[j]) + sigmoidf(accD[j]));
        float4* dst = (float4*)(out + (size_t)n * F + hl16 * 8);
        dst[0] = make_float4(o[0], o[1], o[2], o[3]);
        dst[1] = make_float4(o[4], o[5], o[6], o[7]);
    }
}

extern "C" void kernel_launch(void* const* d_in, const int* in_sizes, int n_in,
                              void* d_out, int out_size, void* d_ws, size_t ws_size,
                              hipStream_t stream) {
    const float* h    = (const float*)d_in[0];
    const float* Wref = (const float*)d_in[1];
    const float* aRef = (const float*)d_in[2];
    const float* Wdir = (const float*)d_in[3];
    const float* aDir = (const float*)d_in[4];
    const int* refNbr = (const int*)d_in[5];
    const int* refCnt = (const int*)d_in[6];
    const int* dirNbr = (const int*)d_in[7];
    const int* dirCnt = (const int*)d_in[8];
    float* out = (float*)d_out;
    const int N = in_sizes[0] / F;

    const size_t NF = (size_t)N * F;
    unsigned char* whRef = (unsigned char*)d_ws;            // NF fp8
    unsigned char* whDir = whRef + NF;                      // NF fp8
    float* sRef = (float*)(whDir + NF);
    float* tRef = sRef + N;
    float* sDir = tRef + N;
    float* tDir = sDir + N;
    unsigned short* wT = (unsigned short*)(tDir + N);       // 2*128*128 bf16, pre-swizzled

    prep_w<<<128, 256, 0, stream>>>(Wref, Wdir, wT);
    gemm_wh<<<(N + 63) / 64, 256, 0, stream>>>(h, wT, aRef, aDir, whRef, whDir,
                                               sRef, tRef, sDir, tDir, N);
    gather_attn<<<(N + 3) / 4, 256, 0, stream>>>(whRef, whDir, sRef, tRef, sDir, tDir,
                                                 refNbr, refCnt, dirNbr, dirCnt, out, N);
}

// Round 6
// 246.030 us; speedup vs baseline: 1.5634x; 1.0412x over previous
//
#include <hip/hip_runtime.h>

typedef __attribute__((ext_vector_type(8))) short s16x8;
typedef __attribute__((ext_vector_type(4))) float f32x4;
typedef __attribute__((ext_vector_type(2))) float f32x2;

#define F 128

__device__ __forceinline__ unsigned short f2bf(float f) {
    unsigned int u = __float_as_uint(f);
    u = (u + 0x7fffu + ((u >> 16) & 1u)) >> 16;
    return (unsigned short)u;
}
__device__ __forceinline__ float bflo(unsigned int u) { return __uint_as_float(u << 16); }
__device__ __forceinline__ float bfhi(unsigned int u) { return __uint_as_float(u & 0xffff0000u); }
__device__ __forceinline__ float leaky(float x) { return x >= 0.f ? x : 0.2f * x; }
__device__ __forceinline__ float sigmoidf(float x) { return 1.f / (1.f + __expf(-x)); }

// byte-level XOR swizzle (16B granular within a 128B stripe), keyed on row&7
#define SWZ16(row, b) ((b) ^ (((row) & 7) << 4))

// wave-local LDS fence (LDS here is wave-private; no block barrier needed)
#define WAVE_LDS_FENCE() do { \
    asm volatile("s_waitcnt lgkmcnt(0)" ::: "memory"); \
    __builtin_amdgcn_sched_barrier(0); \
} while (0)

// async global->LDS, 16B per lane (wave-uniform LDS base + lane*16)
__device__ __forceinline__ void glds16(void* lds, const void* g) {
    __builtin_amdgcn_global_load_lds(
        (const __attribute__((address_space(1))) unsigned int*)g,
        (__attribute__((address_space(3))) unsigned int*)lds,
        16, 0, 0);
}

// ---------------- kernel 0: transpose + bf16 + pre-swizzle both W ----------------
__global__ __launch_bounds__(256) void prep_w(const float* __restrict__ wRef,
                                              const float* __restrict__ wDir,
                                              unsigned short* __restrict__ wT) {
    int i = blockIdx.x * 256 + threadIdx.x;      // 0..32767
    int m = i >> 14;
    int rr = i & 16383;
    int k = rr >> 7;
    int c = rr & 127;
    const float* W = m ? wDir : wRef;
    wT[m * 16384 + c * 128 + (k ^ (((c & 7) << 3)))] = f2bf(W[k * 128 + c]);
}

// ---------------- fused epilogue: s/t row-dots (f32) + C -> fp8 via wave-local LDS ----------------
__device__ __forceinline__ void epi(const f32x4* acc, unsigned char* cb /*wave-local 4KB bf16*/,
                                    int rowBase, int w, int r, int g, int lane, int N,
                                    const float* __restrict__ aVec,
                                    unsigned char* __restrict__ wh /*fp8, 128B rows*/,
                                    float* __restrict__ sArr, float* __restrict__ tArr) {
    float ps[4] = {0.f, 0.f, 0.f, 0.f}, pt[4] = {0.f, 0.f, 0.f, 0.f};
#pragma unroll
    for (int ct = 0; ct < 8; ++ct) {
        int c = ct * 16 + r;
        float As = aVec[c], At = aVec[128 + c];
#pragma unroll
        for (int q = 0; q < 4; ++q) { ps[q] += acc[ct][q] * As; pt[q] += acc[ct][q] * At; }
    }
#pragma unroll
    for (int off = 1; off <= 8; off <<= 1) {
#pragma unroll
        for (int q = 0; q < 4; ++q) {
            ps[q] += __shfl_xor(ps[q], off);
            pt[q] += __shfl_xor(pt[q], off);
        }
    }
    if (r == 0) {
#pragma unroll
        for (int q = 0; q < 4; ++q) {
            int row = rowBase + w * 16 + g * 4 + q;
            if (row < N) { sArr[row] = ps[q]; tArr[row] = pt[q]; }
        }
    }
    // ---- C -> wave-local LDS (bf16, swizzled) ----
#pragma unroll
    for (int ct = 0; ct < 8; ++ct) {
#pragma unroll
        for (int q = 0; q < 4; ++q) {
            int lrow = g * 4 + q;
            int xb = (ct * 16 + r) * 2;
            *(unsigned short*)(cb + lrow * 256 + SWZ16(lrow, xb)) = f2bf(acc[ct][q]);
        }
    }
    // ---- read back linear (deswizzled) -> fp8 pack -> coalesced 8B stores ----
#pragma unroll
    for (int i = 0; i < 4; ++i) {
        int off = i * 1024 + lane * 16;
        int lrow = off >> 8, x = off & 255;
        uint4 v = *(const uint4*)(cb + lrow * 256 + SWZ16(lrow, x));
        int pk0 = __builtin_amdgcn_cvt_pk_fp8_f32(bflo(v.x), bfhi(v.x), 0, false);
        pk0 = __builtin_amdgcn_cvt_pk_fp8_f32(bflo(v.y), bfhi(v.y), pk0, true);
        int pk1 = __builtin_amdgcn_cvt_pk_fp8_f32(bflo(v.z), bfhi(v.z), 0, false);
        pk1 = __builtin_amdgcn_cvt_pk_fp8_f32(bflo(v.w), bfhi(v.w), pk1, true);
        int grow = rowBase + w * 16 + lrow;
        if (grow < N) *(uint2*)(wh + (size_t)grow * 128 + (x >> 1)) = make_uint2((unsigned)pk0, (unsigned)pk1);
    }
}

// ---------------- kernel 1: MFMA GEMM, both matrices, fused s/t + fp8 Wh ----------------
__global__ __launch_bounds__(256) void gemm_wh(const float* __restrict__ h,
                                               const unsigned short* __restrict__ wT,
                                               const float* __restrict__ aRefG,
                                               const float* __restrict__ aDirG,
                                               unsigned char* __restrict__ whRef,
                                               unsigned char* __restrict__ whDir,
                                               float* __restrict__ sRef, float* __restrict__ tRef,
                                               float* __restrict__ sDir, float* __restrict__ tDir,
                                               int N) {
    __shared__ unsigned char lds[49152];
    const int tid = threadIdx.x;
    const int lane = tid & 63, w = tid >> 6;
    const int r = lane & 15, g = lane >> 4;
    const int rowBase = blockIdx.x * 64;

#pragma unroll
    for (int it = 0; it < 8; ++it) {
        int lin = it * 4096 + tid * 16;
        glds16(lds + 16384 + lin, (const char*)wT + lin);
    }
    float4 av[4][2];
#pragma unroll
    for (int it = 0; it < 4; ++it) {
        int lin = it * 4096 + tid * 16;
        int arow = lin >> 8, x = lin & 255;
        int grow = min(rowBase + arow, N - 1);
        const char* src = (const char*)h + (size_t)grow * 512 + x * 2;
        av[it][0] = *(const float4*)(src);
        av[it][1] = *(const float4*)(src + 16);
    }
#pragma unroll
    for (int it = 0; it < 4; ++it) {
        int lin = it * 4096 + tid * 16;
        int arow = lin >> 8, x = lin & 255;
        s16x8 a;
        a[0] = (short)f2bf(av[it][0].x); a[1] = (short)f2bf(av[it][0].y);
        a[2] = (short)f2bf(av[it][0].z); a[3] = (short)f2bf(av[it][0].w);
        a[4] = (short)f2bf(av[it][1].x); a[5] = (short)f2bf(av[it][1].y);
        a[6] = (short)f2bf(av[it][1].z); a[7] = (short)f2bf(av[it][1].w);
        *(s16x8*)(lds + arow * 256 + SWZ16(arow, x)) = a;
    }
    __syncthreads();

    s16x8 afr[4];
    {
        const int arow = w * 16 + r;
#pragma unroll
        for (int kt = 0; kt < 4; ++kt)
            afr[kt] = *(const s16x8*)(lds + arow * 256 + SWZ16(arow, kt * 64 + g * 16));
    }
    unsigned char* cb = lds + w * 4096;

    {
        f32x4 acc[8];
#pragma unroll
        for (int ct = 0; ct < 8; ++ct) acc[ct] = (f32x4){0.f, 0.f, 0.f, 0.f};
#pragma unroll
        for (int kt = 0; kt < 4; ++kt) {
#pragma unroll
            for (int ct = 0; ct < 8; ++ct) {
                int c = ct * 16 + r;
                s16x8 b = *(const s16x8*)(lds + 16384 + c * 256 + SWZ16(c, kt * 64 + g * 16));
                acc[ct] = __builtin_amdgcn_mfma_f32_16x16x32_bf16(afr[kt], b, acc[ct], 0, 0, 0);
            }
        }
        epi(acc, cb, rowBase, w, r, g, lane, N, aRefG, whRef, sRef, tRef);
    }
    __syncthreads();
#pragma unroll
    for (int it = 0; it < 8; ++it) {
        int lin = it * 4096 + tid * 16;
        glds16(lds + 16384 + lin, (const char*)wT + 32768 + lin);
    }
    __syncthreads();
    {
        f32x4 acc[8];
#pragma unroll
        for (int ct = 0; ct < 8; ++ct) acc[ct] = (f32x4){0.f, 0.f, 0.f, 0.f};
#pragma unroll
        for (int kt = 0; kt < 4; ++kt) {
#pragma unroll
            for (int ct = 0; ct < 8; ++ct) {
                int c = ct * 16 + r;
                s16x8 b = *(const s16x8*)(lds + 16384 + c * 256 + SWZ16(c, kt * 64 + g * 16));
                acc[ct] = __builtin_amdgcn_mfma_f32_16x16x32_bf16(afr[kt], b, acc[ct], 0, 0, 0);
            }
        }
        epi(acc, cb, rowBase, w, r, g, lane, N, aDirG, whDir, sDir, tDir);
    }
}

// ---------------- kernel 2: gather + attention, latency-pipelined ----------------
// Pipeline: indices -> compact -> ISSUE all row loads -> (t-gather + softmax in the
// shadow of the row loads) -> coef*row FMA -> combine. All LDS wave-private; no
// block barriers.
__device__ __forceinline__ void acc8f8(float* a, uint2 u, float c) {
    f32x2 p0 = __builtin_amdgcn_cvt_pk_f32_fp8((int)u.x, false);
    f32x2 p1 = __builtin_amdgcn_cvt_pk_f32_fp8((int)u.x, true);
    f32x2 p2 = __builtin_amdgcn_cvt_pk_f32_fp8((int)u.y, false);
    f32x2 p3 = __builtin_amdgcn_cvt_pk_f32_fp8((int)u.y, true);
    a[0] += c * p0[0]; a[1] += c * p0[1];
    a[2] += c * p1[0]; a[3] += c * p1[1];
    a[4] += c * p2[0]; a[5] += c * p2[1];
    a[6] += c * p3[0]; a[7] += c * p3[1];
}

__global__ __launch_bounds__(256) void gather_attn(
    const unsigned char* __restrict__ whRef, const unsigned char* __restrict__ whDir,
    const float* __restrict__ sRef, const float* __restrict__ tRef,
    const float* __restrict__ sDir, const float* __restrict__ tDir,
    const int* __restrict__ refNbr, const int* __restrict__ refCnt,
    const int* __restrict__ dirNbr, const int* __restrict__ dirCnt,
    float* __restrict__ out, int N) {
    __shared__ int   s_idx[4][72];    // wave-private: [0..Lr) compacted ref, [40..40+dcnt) dir
    __shared__ float s_coef[4][72];

    const int wid = threadIdx.x >> 6;
    const int lane = threadIdx.x & 63;
    const int q = lane >> 4, hl16 = lane & 15;
    const int d = lane >> 4, kk = lane & 15;
    const int n_raw = blockIdx.x * 4 + wid;
    const int n = min(n_raw, N - 1);

    // ---- phase 1: independent loads (counts, index lists, self scalars) ----
    int cnt = refCnt[n * 4 + d];                       // cnt <= 10 always
    int idxR = (kk < 10) ? refNbr[(size_t)n * 40 + d * 10 + kk] : 0;
    int dcnt = dirCnt[n];
    int idxD = (lane < 32) ? dirNbr[(size_t)n * 32 + lane] : 0;
    float sR = sRef[n], sD = sDir[n];

    // ---- compact ref indices (validity known without any t data) ----
    bool validR = kk < cnt;
    unsigned long long mask = __ballot(validR);
    int pos = (int)__popcll(mask & ((1ull << lane) - 1ull));
    int Lr = (int)__popcll(mask);
    if (validR) s_idx[wid][pos] = idxR;
    if (lane < 32) s_idx[wid][40 + lane] = idxD;
    WAVE_LDS_FENCE();

    // ---- phase 2: ISSUE all row loads now (held in regs; consumed after softmax) ----
    uint2 uR[10];
#pragma unroll
    for (int j = 0; j < 10; ++j) {
        int e = j * 4 + q;
        if (e < Lr)
            uR[j] = *(const uint2*)(whRef + ((size_t)(unsigned)s_idx[wid][e] << 7) + (hl16 << 3));
    }
    uint2 uD[8];
#pragma unroll
    for (int j = 0; j < 8; ++j) {
        int e = j * 4 + q;
        if (e < dcnt)
            uD[j] = *(const uint2*)(whDir + ((size_t)(unsigned)s_idx[wid][40 + e] << 7) + (hl16 << 3));
    }

    // ---- phase 3: logits + softmax (t-gathers run in the shadow of row loads) ----
    float tv = validR ? tRef[idxR] : 0.f;
    float sum = tv;
    sum += __shfl_xor(sum, 1); sum += __shfl_xor(sum, 2);
    sum += __shfl_xor(sum, 4); sum += __shfl_xor(sum, 8);
    float rc = 1.f / (float)max(cnt, 1);
    float e = leaky(sR + sum * rc);
    float mx = fmaxf(e, __shfl_xor(e, 16)); mx = fmaxf(mx, __shfl_xor(mx, 32));
    float wgt = __expf(e - mx);
    float den = wgt + __shfl_xor(wgt, 16); den += __shfl_xor(den, 32);
    float coefR = wgt / den * rc;
    if (validR) s_coef[wid][pos] = coefR;

    float eD = -1e30f;
    float tD = (lane < 32 && lane < dcnt) ? tDir[idxD] : 0.f;
    if (lane < 32 && lane < dcnt) eD = leaky(sD + tD);
    float mD = eD;
#pragma unroll
    for (int off = 16; off; off >>= 1) mD = fmaxf(mD, __shfl_xor(mD, off, 32));
    float wD = (lane < dcnt) ? __expf(eD - mD) : 0.f;
    float dD = wD;
#pragma unroll
    for (int off = 16; off; off >>= 1) dD += __shfl_xor(dD, off, 32);
    if (lane < 32 && lane < dcnt) s_coef[wid][40 + lane] = wD / dD;
    WAVE_LDS_FENCE();

    // ---- phase 4: weighted accumulate (rows already in flight/arrived) ----
    float accR[8] = {0.f, 0.f, 0.f, 0.f, 0.f, 0.f, 0.f, 0.f};
#pragma unroll
    for (int j = 0; j < 10; ++j) {
        int e = j * 4 + q;
        if (e < Lr) acc8f8(accR, uR[j], s_coef[wid][e]);
    }
    float accD[8] = {0.f, 0.f, 0.f, 0.f, 0.f, 0.f, 0.f, 0.f};
#pragma unroll
    for (int j = 0; j < 8; ++j) {
        int e = j * 4 + q;
        if (e < dcnt) acc8f8(accD, uD[j], s_coef[wid][40 + e]);
    }

    // ---- combine quarters + write ----
#pragma unroll
    for (int j = 0; j < 8; ++j) {
        accR[j] += __shfl_xor(accR[j], 16); accR[j] += __shfl_xor(accR[j], 32);
        accD[j] += __shfl_xor(accD[j], 16); accD[j] += __shfl_xor(accD[j], 32);
    }
    if (n_raw < N && q == 0) {
        float o[8];
#pragma unroll
        for (int j = 0; j < 8; ++j) o[j] = 0.5f * (sigmoidf(accR[j]) + sigmoidf(accD[j]));
        float4* dst = (float4*)(out + (size_t)n * F + hl16 * 8);
        dst[0] = make_float4(o[0], o[1], o[2], o[3]);
        dst[1] = make_float4(o[4], o[5], o[6], o[7]);
    }
}

extern "C" void kernel_launch(void* const* d_in, const int* in_sizes, int n_in,
                              void* d_out, int out_size, void* d_ws, size_t ws_size,
                              hipStream_t stream) {
    const float* h    = (const float*)d_in[0];
    const float* Wref = (const float*)d_in[1];
    const float* aRef = (const float*)d_in[2];
    const float* Wdir = (const float*)d_in[3];
    const float* aDir = (const float*)d_in[4];
    const int* refNbr = (const int*)d_in[5];
    const int* refCnt = (const int*)d_in[6];
    const int* dirNbr = (const int*)d_in[7];
    const int* dirCnt = (const int*)d_in[8];
    float* out = (float*)d_out;
    const int N = in_sizes[0] / F;

    const size_t NF = (size_t)N * F;
    unsigned char* whRef = (unsigned char*)d_ws;            // NF fp8
    unsigned char* whDir = whRef + NF;                      // NF fp8
    float* sRef = (float*)(whDir + NF);
    float* tRef = sRef + N;
    float* sDir = tRef + N;
    float* tDir = sDir + N;
    unsigned short* wT = (unsigned short*)(tDir + N);       // 2*128*128 bf16, pre-swizzled

    prep_w<<<128, 256, 0, stream>>>(Wref, Wdir, wT);
    gemm_wh<<<(N + 63) / 64, 256, 0, stream>>>(h, wT, aRef, aDir, whRef, whDir,
                                               sRef, tRef, sDir, tDir, N);
    gather_attn<<<(N + 3) / 4, 256, 0, stream>>>(whRef, whDir, sRef, tRef, sDir, tDir,
                                                 refNbr, refCnt, dirNbr, dirCnt, out, N);
}